// Round 2
// baseline (4151.461 us; speedup 1.0000x reference)
//
#include <hip/hip_runtime.h>
#include <cstdint>
#include <cstddef>

// Problem constants (fixed by setup_inputs)
#define BB 4
#define TT 2048
#define EE 1024
#define MM 2048
#define CHUNKS 32
#define CLEN (TT/CHUNKS)   // 64

__device__ __forceinline__ float sigf(float v) { return 1.0f / (1.0f + __expf(-v)); }

// ---------------- LayerNorm: one 256-thread block per row of E=1024 ----------------
__global__ __launch_bounds__(256) void ln_kernel(const float* __restrict__ x,
                                                 const float* __restrict__ w,
                                                 const float* __restrict__ b,
                                                 float* __restrict__ y)
{
    int row = blockIdx.x;
    int tid = threadIdx.x;
    const float4* x4 = (const float4*)(x + (size_t)row * EE);
    float4 v = x4[tid];
    float s  = v.x + v.y + v.z + v.w;
    float s2 = v.x*v.x + v.y*v.y + v.z*v.z + v.w*v.w;
    #pragma unroll
    for (int o = 32; o > 0; o >>= 1) {
        s  += __shfl_down(s, o);
        s2 += __shfl_down(s2, o);
    }
    __shared__ float ls[10];
    int wave = tid >> 6, lane = tid & 63;
    if (lane == 0) { ls[wave] = s; ls[4 + wave] = s2; }
    __syncthreads();
    if (tid == 0) {
        float ts  = ls[0] + ls[1] + ls[2] + ls[3];
        float ts2 = ls[4] + ls[5] + ls[6] + ls[7];
        float mu  = ts * (1.0f / EE);
        float var = ts2 * (1.0f / EE) - mu * mu;
        ls[8] = mu;
        ls[9] = rsqrtf(var + 1e-5f);
    }
    __syncthreads();
    float mu = ls[8], inv = ls[9];
    float4 wv = ((const float4*)w)[tid];
    float4 bv = ((const float4*)b)[tid];
    float4 o4;
    o4.x = (v.x - mu) * inv * wv.x + bv.x;
    o4.y = (v.y - mu) * inv * wv.y + bv.y;
    o4.z = (v.z - mu) * inv * wv.z + bv.z;
    o4.w = (v.w - mu) * inv * wv.w + bv.w;
    ((float4*)(y + (size_t)row * EE))[tid] = o4;
}

// ---------------- Tiled fp32 vector GEMM, multi-B fused, fused epilogue ----------------
// Tile 64x64, BK=16, 256 threads, 4x4 micro-tile per thread.
// EPI: 0 = out0=acc0*sig(acc1+b1), out1=sig(acc2+b2), out2=sig(acc3+b3)   (NB=4)
//      1 = out0=acc0*sig(acc1+b1)                                          (NB=2)
//      2 = out0=addsrc+acc0                                                (NB=1)
//      3 = out0=addsrc+acc0+addbias                                        (NB=1)
template<int NB, int EPI>
__global__ __launch_bounds__(256) void gemm_kernel(
    const float* __restrict__ A, int K, int N,
    const float* __restrict__ B0, const float* __restrict__ B1,
    const float* __restrict__ B2, const float* __restrict__ B3,
    const float* __restrict__ bias1, const float* __restrict__ bias2,
    const float* __restrict__ bias3,
    const float* __restrict__ addsrc, const float* __restrict__ addbias,
    float* __restrict__ out0, float* __restrict__ out1, float* __restrict__ out2)
{
    __shared__ float Ast[16][68];        // [k][m], padded
    __shared__ float Bs[NB][16][64];     // [k][n]
    const float* Bp[4] = {B0, B1, B2, B3};

    int tid = threadIdx.x;
    int tx = tid & 15, ty = tid >> 4;
    int m0 = blockIdx.y * 64, n0 = blockIdx.x * 64;
    int arow = tid >> 2, akc = tid & 3;   // A tile: 64 rows x 4 float4s of k
    int brow = tid >> 4, bcol = tid & 15; // B tile: 16 k-rows x 16 float4s of n

    float acc[NB][4][4];
    #pragma unroll
    for (int nb = 0; nb < NB; ++nb)
        #pragma unroll
        for (int i = 0; i < 4; ++i)
            #pragma unroll
            for (int j = 0; j < 4; ++j) acc[nb][i][j] = 0.0f;

    const float* aptr = A + (size_t)(m0 + arow) * K + akc * 4;

    for (int k0 = 0; k0 < K; k0 += 16) {
        float4 av = *(const float4*)(aptr + k0);
        float4 bv[NB];
        #pragma unroll
        for (int nb = 0; nb < NB; ++nb)
            bv[nb] = *(const float4*)(Bp[nb] + (size_t)(k0 + brow) * N + n0 + bcol * 4);
        __syncthreads();  // previous iteration's LDS reads done
        Ast[akc*4+0][arow] = av.x;
        Ast[akc*4+1][arow] = av.y;
        Ast[akc*4+2][arow] = av.z;
        Ast[akc*4+3][arow] = av.w;
        #pragma unroll
        for (int nb = 0; nb < NB; ++nb)
            *(float4*)&Bs[nb][brow][bcol*4] = bv[nb];
        __syncthreads();
        #pragma unroll
        for (int kk = 0; kk < 16; ++kk) {
            float4 a = *(const float4*)&Ast[kk][ty*4];
            float ar[4] = {a.x, a.y, a.z, a.w};
            #pragma unroll
            for (int nb = 0; nb < NB; ++nb) {
                float4 b = *(const float4*)&Bs[nb][kk][tx*4];
                float br[4] = {b.x, b.y, b.z, b.w};
                #pragma unroll
                for (int i = 0; i < 4; ++i)
                    #pragma unroll
                    for (int j = 0; j < 4; ++j)
                        acc[nb][i][j] += ar[i] * br[j];
            }
        }
    }

    int col = n0 + tx * 4;
    float b1a[4], b2a[4], b3a[4], aba[4];
    if constexpr (EPI == 0 || EPI == 1) { *(float4*)b1a = *(const float4*)&bias1[col]; }
    if constexpr (EPI == 0) {
        *(float4*)b2a = *(const float4*)&bias2[col];
        *(float4*)b3a = *(const float4*)&bias3[col];
    }
    if constexpr (EPI == 3) { *(float4*)aba = *(const float4*)&addbias[col]; }

    #pragma unroll
    for (int i = 0; i < 4; ++i) {
        size_t o = (size_t)(m0 + ty * 4 + i) * N + col;
        if constexpr (EPI == 0) {
            float r0[4], r1[4], r2[4];
            #pragma unroll
            for (int j = 0; j < 4; ++j) {
                r0[j] = acc[0][i][j] * sigf(acc[1][i][j] + b1a[j]);
                r1[j] = sigf(acc[2][i][j] + b2a[j]);
                r2[j] = sigf(acc[3][i][j] + b3a[j]);
            }
            *(float4*)&out0[o] = *(float4*)r0;
            *(float4*)&out1[o] = *(float4*)r1;
            *(float4*)&out2[o] = *(float4*)r2;
        } else if constexpr (EPI == 1) {
            float r0[4];
            #pragma unroll
            for (int j = 0; j < 4; ++j)
                r0[j] = acc[0][i][j] * sigf(acc[1][i][j] + b1a[j]);
            *(float4*)&out0[o] = *(float4*)r0;
        } else if constexpr (EPI == 2) {
            float sa[4];
            *(float4*)sa = *(const float4*)&addsrc[o];
            float r0[4];
            #pragma unroll
            for (int j = 0; j < 4; ++j) r0[j] = sa[j] + acc[0][i][j];
            *(float4*)&out0[o] = *(float4*)r0;
        } else {
            float sa[4];
            *(float4*)sa = *(const float4*)&addsrc[o];
            float r0[4];
            #pragma unroll
            for (int j = 0; j < 4; ++j) r0[j] = sa[j] + acc[0][i][j] + aba[j];
            *(float4*)&out0[o] = *(float4*)r0;
        }
    }
}

// ---------------- Chunked linear-recurrence scan (h = r*h + y), ONE batch ----------------
// Y,R point at a [T, M] slab. Chains = M (=2048), chunks = 32 of length 64.
// Pass 1: per (chunk, chain): a = prod r, s = chunk-local scan with h0=0
__global__ __launch_bounds__(256) void scan_pass1(const float* __restrict__ Y,
                                                  const float* __restrict__ R,
                                                  float* __restrict__ Ac,
                                                  float* __restrict__ Sc)
{
    int idx = blockIdx.x * 256 + threadIdx.x;     // 0 .. MM*CHUNKS-1
    int m = idx & (MM - 1);
    int c = idx >> 11;                            // MM = 2^11
    float a = 1.0f, s = 0.0f;
    int t0 = c * CLEN;
    for (int t = t0; t < t0 + CLEN; ++t) {
        size_t ad = (size_t)t * MM + m;
        float r = R[ad], yv = Y[ad];
        s = r * s + yv;
        a *= r;
    }
    Ac[idx] = a;
    Sc[idx] = s;
}

// Pass 2: sequential combine over chunks; emits chunk-start h and final mem_out
__global__ __launch_bounds__(256) void scan_pass2(const float* __restrict__ mem,
                                                  const float* __restrict__ Ac,
                                                  const float* __restrict__ Sc,
                                                  float* __restrict__ H0,
                                                  float* __restrict__ memout)
{
    int m = blockIdx.x * 256 + threadIdx.x;       // 0..MM-1
    float h = mem[m];
    for (int c = 0; c < CHUNKS; ++c) {
        int idx = c * MM + m;
        H0[idx] = h;
        h = Ac[idx] * h + Sc[idx];
    }
    memout[m] = h;
}

// Pass 3: recompute chunk scan with correct h0, emit g = softsign(h)*og (in place over Y)
__global__ __launch_bounds__(256) void scan_pass3(const float* Y,
                                                  const float* __restrict__ R,
                                                  const float* __restrict__ OG,
                                                  const float* __restrict__ H0,
                                                  float* G)
{
    int idx = blockIdx.x * 256 + threadIdx.x;
    int m = idx & (MM - 1);
    int c = idx >> 11;
    float h = H0[idx];
    int t0 = c * CLEN;
    for (int t = t0; t < t0 + CLEN; ++t) {
        size_t ad = (size_t)t * MM + m;
        float r = R[ad], yv = Y[ad];
        h = r * h + yv;
        float g = h / (1.0f + fabsf(h)) * OG[ad];
        G[ad] = g;
    }
}

extern "C" void kernel_launch(void* const* d_in, const int* in_sizes, int n_in,
                              void* d_out, int out_size, void* d_ws, size_t ws_size,
                              hipStream_t stream)
{
    const float* x     = (const float*)d_in[0];
    const float* mem   = (const float*)d_in[1];
    const float* ln1_w = (const float*)d_in[2];
    const float* ln1_b = (const float*)d_in[3];
    const float* wf_w  = (const float*)d_in[4];
    const float* wf_b  = (const float*)d_in[5];
    const float* wi_w  = (const float*)d_in[6];
    const float* wig_w = (const float*)d_in[7];
    const float* wig_b = (const float*)d_in[8];
    const float* wog_w = (const float*)d_in[9];
    const float* wog_b = (const float*)d_in[10];
    const float* wo_w  = (const float*)d_in[11];
    const float* ln2_w = (const float*)d_in[12];
    const float* ln2_b = (const float*)d_in[13];
    const float* fwi_w = (const float*)d_in[14];
    const float* fwg_w = (const float*)d_in[15];
    const float* fwg_b = (const float*)d_in[16];
    const float* fwo_w = (const float*)d_in[17];
    const float* fwo_b = (const float*)d_in[18];
    float* out = (float*)d_out;          // [B*T*E] x_out, then [B*M] mem_out
    (void)in_sizes; (void)n_in; (void)out_size; (void)ws_size;

    // Per-batch workspace (reused for all 4 batches): ~68 MB total
    float* ws  = (float*)d_ws;
    float* y   = ws;                  // 2048*1024 = 2,097,152
    float* yi  = y  + 2097152;        // 2048*2048 = 4,194,304 (g in place later)
    float* rr  = yi + 4194304;        // 2048*2048
    float* og  = rr + 4194304;        // 2048*2048
    float* x2  = og + 4194304;        // 2048*1024
    float* Ac  = x2 + 2097152;        // 32*2048 = 65,536
    float* Sc  = Ac + 65536;
    float* H0  = Sc + 65536;
    // end = H0 + 65536 -> 17,039,360 floats = 68.2 MB

    const int R = TT;                 // rows per batch

    for (int b = 0; b < BB; ++b) {
        const float* xb   = x   + (size_t)b * TT * EE;
        const float* memb = mem + (size_t)b * MM;
        float* outb       = out + (size_t)b * TT * EE;
        float* memoutb    = out + (size_t)BB * TT * EE + (size_t)b * MM;

        // 1. y = LN(x)
        ln_kernel<<<R, 256, 0, stream>>>(xb, ln1_w, ln1_b, y);

        // 2. Fused 4-way gate GEMM:
        //    yi = (y@wi)*sig(y@wig+wig_b); rr = sig(y@wf+wf_b); og = sig(y@wog+wog_b)
        gemm_kernel<4, 0><<<dim3(MM / 64, R / 64), 256, 0, stream>>>(
            y, EE, MM,
            wi_w, wig_w, wf_w, wog_w,
            wig_b, wf_b, wog_b,
            nullptr, nullptr,
            yi, rr, og);

        // 3-5. scan h = r*h + yi ; g = softsign(h)*og ; mem_out
        scan_pass1<<<MM * CHUNKS / 256, 256, 0, stream>>>(yi, rr, Ac, Sc);
        scan_pass2<<<MM / 256, 256, 0, stream>>>(memb, Ac, Sc, H0, memoutb);
        scan_pass3<<<MM * CHUNKS / 256, 256, 0, stream>>>(yi, rr, og, H0, yi);

        // 6. x2 = x + g @ wo_w
        gemm_kernel<1, 2><<<dim3(EE / 64, R / 64), 256, 0, stream>>>(
            yi, MM, EE,
            wo_w, nullptr, nullptr, nullptr,
            nullptr, nullptr, nullptr,
            xb, nullptr,
            x2, nullptr, nullptr);

        // 7. z0 = LN(x2)  (into y buffer)
        ln_kernel<<<R, 256, 0, stream>>>(x2, ln2_w, ln2_b, y);

        // 8. zi = (z0@fwi)*sig(z0@fwg+fwg_b)  (into rr buffer)
        gemm_kernel<2, 1><<<dim3(MM / 64, R / 64), 256, 0, stream>>>(
            y, EE, MM,
            fwi_w, fwg_w, nullptr, nullptr,
            fwg_b, nullptr, nullptr,
            nullptr, nullptr,
            rr, nullptr, nullptr);

        // 9. out = x2 + zi @ fwo_w + fwo_b
        gemm_kernel<1, 3><<<dim3(EE / 64, R / 64), 256, 0, stream>>>(
            rr, MM, EE,
            fwo_w, nullptr, nullptr, nullptr,
            nullptr, nullptr, nullptr,
            x2, fwo_b,
            out + (size_t)b * TT * EE, nullptr, nullptr);
    }
}

// Round 4
// 978.568 us; speedup vs baseline: 4.2424x; 4.2424x over previous
//
#include <hip/hip_runtime.h>
#include <cstdint>
#include <cstddef>

// Problem constants (fixed by setup_inputs)
#define BB 4
#define TT 2048
#define EE 1024
#define MM 2048
#define CHUNKS 32
#define CLEN (TT/CHUNKS)   // 64

typedef _Float16 f16x8 __attribute__((ext_vector_type(8)));
typedef float    f32x4 __attribute__((ext_vector_type(4)));

struct alignas(8) h4 { _Float16 x, y, z, w; };

__device__ __forceinline__ float sigf(float v) { return 1.0f / (1.0f + __expf(-v)); }

__device__ __forceinline__ void gload16(const _Float16* g, _Float16* l) {
    __builtin_amdgcn_global_load_lds((const __attribute__((address_space(1))) void*)g,
                                     (__attribute__((address_space(3))) void*)l, 16, 0, 0);
}

// ---------------- LayerNorm: fp32 in, fp16 out; one 256-thr block per row of E=1024 ----------------
__global__ __launch_bounds__(256) void ln16_kernel(const float* __restrict__ x,
                                                   const float* __restrict__ w,
                                                   const float* __restrict__ b,
                                                   _Float16* __restrict__ y)
{
    int row = blockIdx.x;
    int tid = threadIdx.x;
    const float4* x4 = (const float4*)(x + (size_t)row * EE);
    float4 v = x4[tid];
    float s  = v.x + v.y + v.z + v.w;
    float s2 = v.x*v.x + v.y*v.y + v.z*v.z + v.w*v.w;
    #pragma unroll
    for (int o = 32; o > 0; o >>= 1) {
        s  += __shfl_down(s, o);
        s2 += __shfl_down(s2, o);
    }
    __shared__ float ls[10];
    int wave = tid >> 6, lane = tid & 63;
    if (lane == 0) { ls[wave] = s; ls[4 + wave] = s2; }
    __syncthreads();
    if (tid == 0) {
        float ts  = ls[0] + ls[1] + ls[2] + ls[3];
        float ts2 = ls[4] + ls[5] + ls[6] + ls[7];
        float mu  = ts * (1.0f / EE);
        float var = ts2 * (1.0f / EE) - mu * mu;
        ls[8] = mu;
        ls[9] = rsqrtf(var + 1e-5f);
    }
    __syncthreads();
    float mu = ls[8], inv = ls[9];
    float4 wv = ((const float4*)w)[tid];
    float4 bv = ((const float4*)b)[tid];
    h4 o4;
    o4.x = (_Float16)((v.x - mu) * inv * wv.x + bv.x);
    o4.y = (_Float16)((v.y - mu) * inv * wv.y + bv.y);
    o4.z = (_Float16)((v.z - mu) * inv * wv.z + bv.z);
    o4.w = (_Float16)((v.w - mu) * inv * wv.w + bv.w);
    ((h4*)(y + (size_t)row * EE))[tid] = o4;
}

// ---------------- Weight transpose + fp32->fp16 convert: wt[n][k] = (f16)w[k][n] ----------------
__global__ __launch_bounds__(256) void transpose_cvt(const float* __restrict__ w,
                                                     _Float16* __restrict__ wt,
                                                     int K, int N)
{
    __shared__ _Float16 tile[64][66];
    int n0 = blockIdx.x * 64, k0 = blockIdx.y * 64;
    int c = threadIdx.x & 63, r4 = threadIdx.x >> 6;
    #pragma unroll
    for (int i = 0; i < 16; ++i) {
        int r = r4 * 16 + i;
        tile[r][c] = (_Float16)w[(size_t)(k0 + r) * N + n0 + c];
    }
    __syncthreads();
    #pragma unroll
    for (int i = 0; i < 16; ++i) {
        int rr = r4 * 16 + i;
        wt[(size_t)(n0 + rr) * K + k0 + c] = tile[c][rr];
    }
}

// ---------------- Stage ROWS x BK fp16 tile into LDS via global_load_lds (16B), src-side swizzle ----
template<int ROWS, int BK>
__device__ __forceinline__ void stage_tile(const _Float16* __restrict__ g, int ld,
                                           _Float16* lds, int tid)
{
    constexpr int CPR = BK / 8;             // 16B chunks per row
    constexpr int SH  = (CPR == 4) ? 2 : 3; // log2(CPR)
    constexpr int RSH = (BK == 32) ? 1 : 0; // rows per 128B window shift
    constexpr int NCH = ROWS * CPR;
    #pragma unroll
    for (int i = 0; i < NCH / 256; ++i) {
        int c   = i * 256 + tid;
        int row = c >> SH;
        int kc  = c & (CPR - 1);
        int gkc = kc ^ ((row >> RSH) & (CPR - 1));
        gload16(g + (size_t)row * ld + gkc * 8,
                lds + (size_t)(i * 256 + (tid & ~63)) * 8);
    }
}

// ---------------- fp16 MFMA GEMM: C[M x N] = A[M x K] @ B[K x N], B given transposed [N][K] --------
// 4 waves (2x2), per-wave (TM/2 x TN/2) output, 16x16x32 f16 MFMA.
// EPI 0: gridDim.z=2. z=0: o16a = acc0*sig(acc1+b0) ; z=1 (uses B2,B3): o16b=sig(acc0+b1), o16c=sig(acc1+b2)
// EPI 1: o16a = acc0*sig(acc1+b0)
// EPI 2: o32 = addsrc + acc0
// EPI 3: o32 = addsrc + acc0 + b0   (o32 may alias addsrc: same-index read-then-write)
template<int TM, int TN, int BK, int NMAT, int EPI>
__global__ __launch_bounds__(256) void gemm16(
    const _Float16* __restrict__ A, int K, int N,
    const _Float16* __restrict__ B0, const _Float16* __restrict__ B1,
    const _Float16* __restrict__ B2, const _Float16* __restrict__ B3,
    const float* __restrict__ b0, const float* __restrict__ b1, const float* __restrict__ b2,
    const float* __restrict__ addsrc,
    _Float16* __restrict__ o16a, _Float16* __restrict__ o16b, _Float16* __restrict__ o16c,
    float* __restrict__ o32)
{
    constexpr int WM = TM / 2, WN = TN / 2;
    constexpr int FM = WM / 16, FN = WN / 16, KF = BK / 32;
    constexpr int CPR = BK / 8;
    constexpr int RSH = (BK == 32) ? 1 : 0;

    __shared__ alignas(16) _Float16 As[TM * BK];
    __shared__ alignas(16) _Float16 Bs[NMAT][TN * BK];

    int tid  = threadIdx.x;
    int lane = tid & 63, w = tid >> 6;
    int wr = w >> 1, wc = w & 1;
    int m0 = blockIdx.y * TM, n0 = blockIdx.x * TN;
    int lm = lane & 15, lg = lane >> 4;

    const _Float16* Bp[NMAT];
    Bp[0] = B0;
    if constexpr (NMAT == 2) Bp[1] = B1;
    if constexpr (EPI == 0) {
        if (blockIdx.z == 1) { Bp[0] = B2; Bp[1] = B3; }
    }

    const _Float16* Ab = A + (size_t)m0 * K;
    const _Float16* Bb[NMAT];
    #pragma unroll
    for (int mt = 0; mt < NMAT; ++mt) Bb[mt] = Bp[mt] + (size_t)n0 * K;

    f32x4 acc[NMAT][FM][FN];
    #pragma unroll
    for (int mt = 0; mt < NMAT; ++mt)
        #pragma unroll
        for (int fm = 0; fm < FM; ++fm)
            #pragma unroll
            for (int fn = 0; fn < FN; ++fn)
                acc[mt][fm][fn] = (f32x4){0.f, 0.f, 0.f, 0.f};

    for (int kt = 0; kt < K; kt += BK) {
        __syncthreads();
        stage_tile<TM, BK>(Ab + kt, K, As, tid);
        #pragma unroll
        for (int mt = 0; mt < NMAT; ++mt)
            stage_tile<TN, BK>(Bb[mt] + kt, K, &Bs[mt][0], tid);
        __syncthreads();

        #pragma unroll
        for (int kf = 0; kf < KF; ++kf) {
            f16x8 af[FM];
            #pragma unroll
            for (int fm = 0; fm < FM; ++fm) {
                int row = wr * WM + fm * 16 + lm;
                int sc  = (kf * 4 + lg) ^ ((row >> RSH) & (CPR - 1));
                af[fm] = *(const f16x8*)&As[row * BK + sc * 8];
            }
            #pragma unroll
            for (int mt = 0; mt < NMAT; ++mt) {
                #pragma unroll
                for (int fn = 0; fn < FN; ++fn) {
                    int row = wc * WN + fn * 16 + lm;
                    int sc  = (kf * 4 + lg) ^ ((row >> RSH) & (CPR - 1));
                    f16x8 bf = *(const f16x8*)&Bs[mt][row * BK + sc * 8];
                    #pragma unroll
                    for (int fm = 0; fm < FM; ++fm)
                        acc[mt][fm][fn] = __builtin_amdgcn_mfma_f32_16x16x32_f16(
                            af[fm], bf, acc[mt][fm][fn], 0, 0, 0);
                }
            }
        }
    }

    // Epilogue: C/D layout col = lane&15, row = (lane>>4)*4 + q   [m89-verified]
    #pragma unroll
    for (int fn = 0; fn < FN; ++fn) {
        int col = n0 + wc * WN + fn * 16 + lm;
        float bb0 = 0.f, bb1 = 0.f, bb2 = 0.f;
        if constexpr (EPI == 0) {
            if (blockIdx.z == 0) bb0 = b0[col];
            else { bb1 = b1[col]; bb2 = b2[col]; }
        } else if constexpr (EPI == 1) {
            bb0 = b0[col];
        } else if constexpr (EPI == 3) {
            bb0 = b0[col];
        }
        #pragma unroll
        for (int fm = 0; fm < FM; ++fm) {
            #pragma unroll
            for (int q = 0; q < 4; ++q) {
                int row = m0 + wr * WM + fm * 16 + lg * 4 + q;
                size_t o = (size_t)row * N + col;
                float a0 = acc[0][fm][fn][q];
                if constexpr (EPI == 0) {
                    float a1 = acc[1][fm][fn][q];
                    if (blockIdx.z == 0) {
                        o16a[o] = (_Float16)(a0 * sigf(a1 + bb0));
                    } else {
                        o16b[o] = (_Float16)sigf(a0 + bb1);
                        o16c[o] = (_Float16)sigf(a1 + bb2);
                    }
                } else if constexpr (EPI == 1) {
                    float a1 = acc[1][fm][fn][q];
                    o16a[o] = (_Float16)(a0 * sigf(a1 + bb0));
                } else if constexpr (EPI == 2) {
                    o32[o] = addsrc[o] + a0;
                } else {
                    o32[o] = addsrc[o] + a0 + bb0;
                }
            }
        }
    }
}

// ---------------- Chunked linear-recurrence scan (h = r*h + y), ONE batch, fp16 I/O ----------------
__global__ __launch_bounds__(256) void scan_pass1(const _Float16* __restrict__ Y,
                                                  const _Float16* __restrict__ R,
                                                  float* __restrict__ Ac,
                                                  float* __restrict__ Sc)
{
    int idx = blockIdx.x * 256 + threadIdx.x;     // 0 .. MM*CHUNKS-1
    int m = idx & (MM - 1);
    int c = idx >> 11;                            // MM = 2^11
    float a = 1.0f, s = 0.0f;
    int t0 = c * CLEN;
    for (int t = t0; t < t0 + CLEN; ++t) {
        size_t ad = (size_t)t * MM + m;
        float r = (float)R[ad], yv = (float)Y[ad];
        s = r * s + yv;
        a *= r;
    }
    Ac[idx] = a;
    Sc[idx] = s;
}

__global__ __launch_bounds__(256) void scan_pass2(const float* __restrict__ mem,
                                                  const float* __restrict__ Ac,
                                                  const float* __restrict__ Sc,
                                                  float* __restrict__ H0,
                                                  float* __restrict__ memout)
{
    int m = blockIdx.x * 256 + threadIdx.x;       // 0..MM-1
    float h = mem[m];
    for (int c = 0; c < CHUNKS; ++c) {
        int idx = c * MM + m;
        H0[idx] = h;
        h = Ac[idx] * h + Sc[idx];
    }
    memout[m] = h;
}

// Pass 3: recompute chunk scan with h0, emit g = softsign(h)*og IN PLACE over Y (same elem, same thread)
__global__ __launch_bounds__(256) void scan_pass3(_Float16* __restrict__ Y,
                                                  const _Float16* __restrict__ R,
                                                  const _Float16* __restrict__ OG,
                                                  const float* __restrict__ H0)
{
    int idx = blockIdx.x * 256 + threadIdx.x;
    int m = idx & (MM - 1);
    int c = idx >> 11;
    float h = H0[idx];
    int t0 = c * CLEN;
    for (int t = t0; t < t0 + CLEN; ++t) {
        size_t ad = (size_t)t * MM + m;
        float r = (float)R[ad], yv = (float)Y[ad];
        h = r * h + yv;
        float g = h / (1.0f + fabsf(h)) * (float)OG[ad];
        Y[ad] = (_Float16)g;
    }
}

extern "C" void kernel_launch(void* const* d_in, const int* in_sizes, int n_in,
                              void* d_out, int out_size, void* d_ws, size_t ws_size,
                              hipStream_t stream)
{
    const float* x     = (const float*)d_in[0];
    const float* mem   = (const float*)d_in[1];
    const float* ln1_w = (const float*)d_in[2];
    const float* ln1_b = (const float*)d_in[3];
    const float* wf_w  = (const float*)d_in[4];
    const float* wf_b  = (const float*)d_in[5];
    const float* wi_w  = (const float*)d_in[6];
    const float* wig_w = (const float*)d_in[7];
    const float* wig_b = (const float*)d_in[8];
    const float* wog_w = (const float*)d_in[9];
    const float* wog_b = (const float*)d_in[10];
    const float* wo_w  = (const float*)d_in[11];
    const float* ln2_w = (const float*)d_in[12];
    const float* ln2_b = (const float*)d_in[13];
    const float* fwi_w = (const float*)d_in[14];
    const float* fwg_w = (const float*)d_in[15];
    const float* fwg_b = (const float*)d_in[16];
    const float* fwo_w = (const float*)d_in[17];
    const float* fwo_b = (const float*)d_in[18];
    float* out = (float*)d_out;          // [B*T*E] x_out, then [B*M] mem_out
    (void)in_sizes; (void)n_in; (void)out_size; (void)ws_size;

    // ---- workspace layout (~60.9 MB; x2 aliases the output slab per batch) ----
    char* p = (char*)d_ws;
    _Float16* wi_t  = (_Float16*)p; p += (size_t)MM * EE * 2;   // [2048][1024] each 4 MB
    _Float16* wig_t = (_Float16*)p; p += (size_t)MM * EE * 2;
    _Float16* wf_t  = (_Float16*)p; p += (size_t)MM * EE * 2;
    _Float16* wog_t = (_Float16*)p; p += (size_t)MM * EE * 2;
    _Float16* wo_t  = (_Float16*)p; p += (size_t)EE * MM * 2;   // [1024][2048]
    _Float16* fwi_t = (_Float16*)p; p += (size_t)MM * EE * 2;
    _Float16* fwg_t = (_Float16*)p; p += (size_t)MM * EE * 2;
    _Float16* fwo_t = (_Float16*)p; p += (size_t)EE * MM * 2;   // [1024][2048]
    _Float16* y16   = (_Float16*)p; p += (size_t)TT * EE * 2;   // 4 MB (z16 aliases)
    _Float16* yi16  = (_Float16*)p; p += (size_t)TT * MM * 2;   // 8 MB (g16 in-place)
    _Float16* rr16  = (_Float16*)p; p += (size_t)TT * MM * 2;   // 8 MB
    _Float16* og16  = (_Float16*)p; p += (size_t)TT * MM * 2;   // 8 MB (zi16 aliases)
    float*    Ac    = (float*)p;    p += (size_t)CHUNKS * MM * 4;
    float*    Sc    = (float*)p;    p += (size_t)CHUNKS * MM * 4;
    float*    H0    = (float*)p;    p += (size_t)CHUNKS * MM * 4;

    // ---- weight convert + transpose (once per call) ----
    transpose_cvt<<<dim3(MM/64, EE/64), 256, 0, stream>>>(wi_w,  wi_t,  EE, MM);
    transpose_cvt<<<dim3(MM/64, EE/64), 256, 0, stream>>>(wig_w, wig_t, EE, MM);
    transpose_cvt<<<dim3(MM/64, EE/64), 256, 0, stream>>>(wf_w,  wf_t,  EE, MM);
    transpose_cvt<<<dim3(MM/64, EE/64), 256, 0, stream>>>(wog_w, wog_t, EE, MM);
    transpose_cvt<<<dim3(EE/64, MM/64), 256, 0, stream>>>(wo_w,  wo_t,  MM, EE);
    transpose_cvt<<<dim3(MM/64, EE/64), 256, 0, stream>>>(fwi_w, fwi_t, EE, MM);
    transpose_cvt<<<dim3(MM/64, EE/64), 256, 0, stream>>>(fwg_w, fwg_t, EE, MM);
    transpose_cvt<<<dim3(EE/64, MM/64), 256, 0, stream>>>(fwo_w, fwo_t, MM, EE);

    for (int b = 0; b < BB; ++b) {
        const float* xb   = x   + (size_t)b * TT * EE;
        const float* memb = mem + (size_t)b * MM;
        float* outb       = out + (size_t)b * TT * EE;
        float* memoutb    = out + (size_t)BB * TT * EE + (size_t)b * MM;
        float* x2         = outb;   // x2 lives in the output slab for this batch

        // 1. y = LN(x) -> fp16
        ln16_kernel<<<TT, 256, 0, stream>>>(xb, ln1_w, ln1_b, y16);

        // 2. Gate GEMMs (2 pairs via z): yi = (y@wi)*sig(y@wig+b); rr = sig(y@wf+b); og = sig(y@wog+b)
        gemm16<64, 128, 32, 2, 0><<<dim3(MM/128, TT/64, 2), 256, 0, stream>>>(
            y16, EE, MM,
            wi_t, wig_t, wf_t, wog_t,
            wig_b, wf_b, wog_b,
            nullptr,
            yi16, rr16, og16, nullptr);

        // 3-5. scan h = r*h + yi ; g = softsign(h)*og (in place over yi16) ; mem_out
        scan_pass1<<<MM * CHUNKS / 256, 256, 0, stream>>>(yi16, rr16, Ac, Sc);
        scan_pass2<<<MM / 256, 256, 0, stream>>>(memb, Ac, Sc, H0, memoutb);
        scan_pass3<<<MM * CHUNKS / 256, 256, 0, stream>>>(yi16, rr16, og16, H0);

        // 6. x2 = x + g @ wo   (x2 == outb)
        gemm16<64, 64, 64, 1, 2><<<dim3(EE/64, TT/64), 256, 0, stream>>>(
            yi16, MM, EE,
            wo_t, nullptr, nullptr, nullptr,
            nullptr, nullptr, nullptr,
            xb,
            nullptr, nullptr, nullptr, x2);

        // 7. z = LN(x2) -> fp16 (into y16)
        ln16_kernel<<<TT, 256, 0, stream>>>(x2, ln2_w, ln2_b, y16);

        // 8. zi = (z@fwi)*sig(z@fwg+b)  (into og16)
        gemm16<64, 128, 32, 2, 1><<<dim3(MM/128, TT/64), 256, 0, stream>>>(
            y16, EE, MM,
            fwi_t, fwg_t, nullptr, nullptr,
            fwg_b, nullptr, nullptr,
            nullptr,
            og16, nullptr, nullptr, nullptr);

        // 9. out = x2 + zi @ fwo + fwo_b  (in place over the output slab; same-index RMW)
        gemm16<64, 64, 64, 1, 3><<<dim3(EE/64, TT/64), 256, 0, stream>>>(
            og16, MM, EE,
            fwo_t, nullptr, nullptr, nullptr,
            fwo_b, nullptr, nullptr,
            x2,
            nullptr, nullptr, nullptr, outb);
    }
}

// Round 5
// 958.586 us; speedup vs baseline: 4.3308x; 1.0208x over previous
//
#include <hip/hip_runtime.h>
#include <cstdint>
#include <cstddef>

// Problem constants (fixed by setup_inputs)
#define BB 4
#define TT 2048
#define EE 1024
#define MM 2048
#define CHUNKS 32
#define CLEN (TT/CHUNKS)   // 64

typedef _Float16 f16x8 __attribute__((ext_vector_type(8)));
typedef float    f32x4 __attribute__((ext_vector_type(4)));

struct alignas(8) h4 { _Float16 x, y, z, w; };

__device__ __forceinline__ float sigf(float v) { return 1.0f / (1.0f + __expf(-v)); }

__device__ __forceinline__ void gload16(const _Float16* g, _Float16* l) {
    __builtin_amdgcn_global_load_lds((const __attribute__((address_space(1))) void*)g,
                                     (__attribute__((address_space(3))) void*)l, 16, 0, 0);
}

// ---------------- LayerNorm: fp32 in, fp16 out; one 256-thr block per row of E=1024 ----------------
__global__ __launch_bounds__(256) void ln16_kernel(const float* __restrict__ x,
                                                   const float* __restrict__ w,
                                                   const float* __restrict__ b,
                                                   _Float16* __restrict__ y)
{
    int row = blockIdx.x;
    int tid = threadIdx.x;
    const float4* x4 = (const float4*)(x + (size_t)row * EE);
    float4 v = x4[tid];
    float s  = v.x + v.y + v.z + v.w;
    float s2 = v.x*v.x + v.y*v.y + v.z*v.z + v.w*v.w;
    #pragma unroll
    for (int o = 32; o > 0; o >>= 1) {
        s  += __shfl_down(s, o);
        s2 += __shfl_down(s2, o);
    }
    __shared__ float ls[10];
    int wave = tid >> 6, lane = tid & 63;
    if (lane == 0) { ls[wave] = s; ls[4 + wave] = s2; }
    __syncthreads();
    if (tid == 0) {
        float ts  = ls[0] + ls[1] + ls[2] + ls[3];
        float ts2 = ls[4] + ls[5] + ls[6] + ls[7];
        float mu  = ts * (1.0f / EE);
        float var = ts2 * (1.0f / EE) - mu * mu;
        ls[8] = mu;
        ls[9] = rsqrtf(var + 1e-5f);
    }
    __syncthreads();
    float mu = ls[8], inv = ls[9];
    float4 wv = ((const float4*)w)[tid];
    float4 bv = ((const float4*)b)[tid];
    h4 o4;
    o4.x = (_Float16)((v.x - mu) * inv * wv.x + bv.x);
    o4.y = (_Float16)((v.y - mu) * inv * wv.y + bv.y);
    o4.z = (_Float16)((v.z - mu) * inv * wv.z + bv.z);
    o4.w = (_Float16)((v.w - mu) * inv * wv.w + bv.w);
    ((h4*)(y + (size_t)row * EE))[tid] = o4;
}

// -------- All 8 weight transposes in ONE dispatch: wt[n][k] = (f16)w[k][n] ----------------
// ids 0-3,5,6: src [1024][2048]; ids 4,7: src [2048][1024]. grid = (512, 8)
__global__ __launch_bounds__(256) void transpose_cvt8(
    const float* __restrict__ w0, const float* __restrict__ w1,
    const float* __restrict__ w2, const float* __restrict__ w3,
    const float* __restrict__ w4, const float* __restrict__ w5,
    const float* __restrict__ w6, const float* __restrict__ w7,
    _Float16* __restrict__ t0, _Float16* __restrict__ t1,
    _Float16* __restrict__ t2, _Float16* __restrict__ t3,
    _Float16* __restrict__ t4, _Float16* __restrict__ t5,
    _Float16* __restrict__ t6, _Float16* __restrict__ t7)
{
    __shared__ _Float16 tile[64][66];
    int id = blockIdx.y;
    const float* w; _Float16* t; int K, N;
    switch (id) {
        case 0: w = w0; t = t0; K = EE; N = MM; break;
        case 1: w = w1; t = t1; K = EE; N = MM; break;
        case 2: w = w2; t = t2; K = EE; N = MM; break;
        case 3: w = w3; t = t3; K = EE; N = MM; break;
        case 4: w = w4; t = t4; K = MM; N = EE; break;
        case 5: w = w5; t = t5; K = EE; N = MM; break;
        case 6: w = w6; t = t6; K = EE; N = MM; break;
        default: w = w7; t = t7; K = MM; N = EE; break;
    }
    int nb = N >> 6;
    int n0 = (blockIdx.x % nb) * 64, k0 = (blockIdx.x / nb) * 64;
    int c = threadIdx.x & 63, r4 = threadIdx.x >> 6;
    #pragma unroll
    for (int i = 0; i < 16; ++i) {
        int r = r4 * 16 + i;
        tile[r][c] = (_Float16)w[(size_t)(k0 + r) * N + n0 + c];
    }
    __syncthreads();
    #pragma unroll
    for (int i = 0; i < 16; ++i) {
        int rr = r4 * 16 + i;
        t[(size_t)(n0 + rr) * K + k0 + c] = tile[c][rr];
    }
}

// ---------------- Stage ROWS x BK fp16 tile into LDS via global_load_lds (16B), src-side swizzle ----
template<int ROWS, int BK>
__device__ __forceinline__ void stage_tile(const _Float16* __restrict__ g, int ld,
                                           _Float16* lds, int tid)
{
    constexpr int CPR = BK / 8;             // 16B chunks per row
    constexpr int SH  = (CPR == 4) ? 2 : 3; // log2(CPR)
    constexpr int RSH = (BK == 32) ? 1 : 0; // rows per 128B window shift
    constexpr int NCH = ROWS * CPR;
    #pragma unroll
    for (int i = 0; i < NCH / 256; ++i) {
        int c   = i * 256 + tid;
        int row = c >> SH;
        int kc  = c & (CPR - 1);
        int gkc = kc ^ ((row >> RSH) & (CPR - 1));
        gload16(g + (size_t)row * ld + gkc * 8,
                lds + (size_t)(i * 256 + (tid & ~63)) * 8);
    }
}

// ---------------- fp16 MFMA GEMM: C[M x N] = A[M x K] @ B[K x N], B given transposed [N][K] --------
// 4 waves (2x2), per-wave (TM/2 x TN/2) output, 16x16x32 f16 MFMA.
// EPI 0: gridDim.z=2. z=0: o16a = acc0*sig(acc1+b0) ; z=1 (uses B2,B3): o16b=sig(acc0+b1), o16c=sig(acc1+b2)
// EPI 1: o16a = acc0*sig(acc1+b0)
// EPI 2: o32 = addsrc + acc0
// EPI 3: o32 = addsrc + acc0 + b0   (o32 may alias addsrc: same-index read-then-write)
template<int TM, int TN, int BK, int NMAT, int EPI>
__global__ __launch_bounds__(256) void gemm16(
    const _Float16* __restrict__ A, int K, int N,
    const _Float16* __restrict__ B0, const _Float16* __restrict__ B1,
    const _Float16* __restrict__ B2, const _Float16* __restrict__ B3,
    const float* __restrict__ b0, const float* __restrict__ b1, const float* __restrict__ b2,
    const float* __restrict__ addsrc,
    _Float16* __restrict__ o16a, _Float16* __restrict__ o16b, _Float16* __restrict__ o16c,
    float* __restrict__ o32)
{
    constexpr int WM = TM / 2, WN = TN / 2;
    constexpr int FM = WM / 16, FN = WN / 16, KF = BK / 32;
    constexpr int CPR = BK / 8;
    constexpr int RSH = (BK == 32) ? 1 : 0;

    __shared__ alignas(16) _Float16 As[TM * BK];
    __shared__ alignas(16) _Float16 Bs[NMAT][TN * BK];

    int tid  = threadIdx.x;
    int lane = tid & 63, w = tid >> 6;
    int wr = w >> 1, wc = w & 1;
    int m0 = blockIdx.y * TM, n0 = blockIdx.x * TN;
    int lm = lane & 15, lg = lane >> 4;

    const _Float16* Bp[NMAT];
    Bp[0] = B0;
    if constexpr (NMAT == 2) Bp[1] = B1;
    if constexpr (EPI == 0) {
        if (blockIdx.z == 1) { Bp[0] = B2; Bp[1] = B3; }
    }

    const _Float16* Ab = A + (size_t)m0 * K;
    const _Float16* Bb[NMAT];
    #pragma unroll
    for (int mt = 0; mt < NMAT; ++mt) Bb[mt] = Bp[mt] + (size_t)n0 * K;

    f32x4 acc[NMAT][FM][FN];
    #pragma unroll
    for (int mt = 0; mt < NMAT; ++mt)
        #pragma unroll
        for (int fm = 0; fm < FM; ++fm)
            #pragma unroll
            for (int fn = 0; fn < FN; ++fn)
                acc[mt][fm][fn] = (f32x4){0.f, 0.f, 0.f, 0.f};

    for (int kt = 0; kt < K; kt += BK) {
        __syncthreads();
        stage_tile<TM, BK>(Ab + kt, K, As, tid);
        #pragma unroll
        for (int mt = 0; mt < NMAT; ++mt)
            stage_tile<TN, BK>(Bb[mt] + kt, K, &Bs[mt][0], tid);
        __syncthreads();

        #pragma unroll
        for (int kf = 0; kf < KF; ++kf) {
            f16x8 af[FM];
            #pragma unroll
            for (int fm = 0; fm < FM; ++fm) {
                int row = wr * WM + fm * 16 + lm;
                int sc  = (kf * 4 + lg) ^ ((row >> RSH) & (CPR - 1));
                af[fm] = *(const f16x8*)&As[row * BK + sc * 8];
            }
            #pragma unroll
            for (int mt = 0; mt < NMAT; ++mt) {
                #pragma unroll
                for (int fn = 0; fn < FN; ++fn) {
                    int row = wc * WN + fn * 16 + lm;
                    int sc  = (kf * 4 + lg) ^ ((row >> RSH) & (CPR - 1));
                    f16x8 bf = *(const f16x8*)&Bs[mt][row * BK + sc * 8];
                    #pragma unroll
                    for (int fm = 0; fm < FM; ++fm)
                        acc[mt][fm][fn] = __builtin_amdgcn_mfma_f32_16x16x32_f16(
                            af[fm], bf, acc[mt][fm][fn], 0, 0, 0);
                }
            }
        }
    }

    // Epilogue: C/D layout col = lane&15, row = (lane>>4)*4 + q   [m89-verified]
    #pragma unroll
    for (int fn = 0; fn < FN; ++fn) {
        int col = n0 + wc * WN + fn * 16 + lm;
        float bb0 = 0.f, bb1 = 0.f, bb2 = 0.f;
        if constexpr (EPI == 0) {
            if (blockIdx.z == 0) bb0 = b0[col];
            else { bb1 = b1[col]; bb2 = b2[col]; }
        } else if constexpr (EPI == 1) {
            bb0 = b0[col];
        } else if constexpr (EPI == 3) {
            bb0 = b0[col];
        }
        #pragma unroll
        for (int fm = 0; fm < FM; ++fm) {
            #pragma unroll
            for (int q = 0; q < 4; ++q) {
                int row = m0 + wr * WM + fm * 16 + lg * 4 + q;
                size_t o = (size_t)row * N + col;
                float a0 = acc[0][fm][fn][q];
                if constexpr (EPI == 0) {
                    float a1 = acc[1][fm][fn][q];
                    if (blockIdx.z == 0) {
                        o16a[o] = (_Float16)(a0 * sigf(a1 + bb0));
                    } else {
                        o16b[o] = (_Float16)sigf(a0 + bb1);
                        o16c[o] = (_Float16)sigf(a1 + bb2);
                    }
                } else if constexpr (EPI == 1) {
                    float a1 = acc[1][fm][fn][q];
                    o16a[o] = (_Float16)(a0 * sigf(a1 + bb0));
                } else if constexpr (EPI == 2) {
                    o32[o] = addsrc[o] + a0;
                } else {
                    o32[o] = addsrc[o] + a0 + bb0;
                }
            }
        }
    }
}

// ---------------- Chunked linear-recurrence scan (h = r*h + y), ONE batch, fp16 I/O ----------------
__global__ __launch_bounds__(256) void scan_pass1(const _Float16* __restrict__ Y,
                                                  const _Float16* __restrict__ R,
                                                  float* __restrict__ Ac,
                                                  float* __restrict__ Sc)
{
    int idx = blockIdx.x * 256 + threadIdx.x;     // 0 .. MM*CHUNKS-1
    int m = idx & (MM - 1);
    int c = idx >> 11;                            // MM = 2^11
    float a = 1.0f, s = 0.0f;
    int t0 = c * CLEN;
    for (int t = t0; t < t0 + CLEN; ++t) {
        size_t ad = (size_t)t * MM + m;
        float r = (float)R[ad], yv = (float)Y[ad];
        s = r * s + yv;
        a *= r;
    }
    Ac[idx] = a;
    Sc[idx] = s;
}

__global__ __launch_bounds__(256) void scan_pass2(const float* __restrict__ mem,
                                                  const float* __restrict__ Ac,
                                                  const float* __restrict__ Sc,
                                                  float* __restrict__ H0,
                                                  float* __restrict__ memout)
{
    int m = blockIdx.x * 256 + threadIdx.x;       // 0..MM-1
    float h = mem[m];
    for (int c = 0; c < CHUNKS; ++c) {
        int idx = c * MM + m;
        H0[idx] = h;
        h = Ac[idx] * h + Sc[idx];
    }
    memout[m] = h;
}

// Pass 3: recompute chunk scan with h0, emit g = softsign(h)*og IN PLACE over Y (same elem, same thread)
__global__ __launch_bounds__(256) void scan_pass3(_Float16* __restrict__ Y,
                                                  const _Float16* __restrict__ R,
                                                  const _Float16* __restrict__ OG,
                                                  const float* __restrict__ H0)
{
    int idx = blockIdx.x * 256 + threadIdx.x;
    int m = idx & (MM - 1);
    int c = idx >> 11;
    float h = H0[idx];
    int t0 = c * CLEN;
    for (int t = t0; t < t0 + CLEN; ++t) {
        size_t ad = (size_t)t * MM + m;
        float r = (float)R[ad], yv = (float)Y[ad];
        h = r * h + yv;
        float g = h / (1.0f + fabsf(h)) * (float)OG[ad];
        Y[ad] = (_Float16)g;
    }
}

extern "C" void kernel_launch(void* const* d_in, const int* in_sizes, int n_in,
                              void* d_out, int out_size, void* d_ws, size_t ws_size,
                              hipStream_t stream)
{
    const float* x     = (const float*)d_in[0];
    const float* mem   = (const float*)d_in[1];
    const float* ln1_w = (const float*)d_in[2];
    const float* ln1_b = (const float*)d_in[3];
    const float* wf_w  = (const float*)d_in[4];
    const float* wf_b  = (const float*)d_in[5];
    const float* wi_w  = (const float*)d_in[6];
    const float* wig_w = (const float*)d_in[7];
    const float* wig_b = (const float*)d_in[8];
    const float* wog_w = (const float*)d_in[9];
    const float* wog_b = (const float*)d_in[10];
    const float* wo_w  = (const float*)d_in[11];
    const float* ln2_w = (const float*)d_in[12];
    const float* ln2_b = (const float*)d_in[13];
    const float* fwi_w = (const float*)d_in[14];
    const float* fwg_w = (const float*)d_in[15];
    const float* fwg_b = (const float*)d_in[16];
    const float* fwo_w = (const float*)d_in[17];
    const float* fwo_b = (const float*)d_in[18];
    float* out = (float*)d_out;          // [B*T*E] x_out, then [B*M] mem_out
    (void)in_sizes; (void)n_in; (void)out_size; (void)ws_size;

    // ---- workspace layout (~60.9 MB; x2 aliases the output slab per batch) ----
    char* p = (char*)d_ws;
    _Float16* wi_t  = (_Float16*)p; p += (size_t)MM * EE * 2;   // [2048][1024] each 4 MB
    _Float16* wig_t = (_Float16*)p; p += (size_t)MM * EE * 2;
    _Float16* wf_t  = (_Float16*)p; p += (size_t)MM * EE * 2;
    _Float16* wog_t = (_Float16*)p; p += (size_t)MM * EE * 2;
    _Float16* wo_t  = (_Float16*)p; p += (size_t)EE * MM * 2;   // [1024][2048]
    _Float16* fwi_t = (_Float16*)p; p += (size_t)MM * EE * 2;
    _Float16* fwg_t = (_Float16*)p; p += (size_t)MM * EE * 2;
    _Float16* fwo_t = (_Float16*)p; p += (size_t)EE * MM * 2;   // [1024][2048]
    _Float16* y16   = (_Float16*)p; p += (size_t)TT * EE * 2;   // 4 MB (z16 aliases)
    _Float16* yi16  = (_Float16*)p; p += (size_t)TT * MM * 2;   // 8 MB (g16 in-place)
    _Float16* rr16  = (_Float16*)p; p += (size_t)TT * MM * 2;   // 8 MB
    _Float16* og16  = (_Float16*)p; p += (size_t)TT * MM * 2;   // 8 MB (zi16 aliases)
    float*    Ac    = (float*)p;    p += (size_t)CHUNKS * MM * 4;
    float*    Sc    = (float*)p;    p += (size_t)CHUNKS * MM * 4;
    float*    H0    = (float*)p;    p += (size_t)CHUNKS * MM * 4;

    // ---- all 8 weight converts/transposes in one dispatch ----
    transpose_cvt8<<<dim3(512, 8), 256, 0, stream>>>(
        wi_w, wig_w, wf_w, wog_w, wo_w, fwi_w, fwg_w, fwo_w,
        wi_t, wig_t, wf_t, wog_t, wo_t, fwi_t, fwg_t, fwo_t);

    for (int b = 0; b < BB; ++b) {
        const float* xb   = x   + (size_t)b * TT * EE;
        const float* memb = mem + (size_t)b * MM;
        float* outb       = out + (size_t)b * TT * EE;
        float* memoutb    = out + (size_t)BB * TT * EE + (size_t)b * MM;
        float* x2         = outb;   // x2 lives in the output slab for this batch

        // 1. y = LN(x) -> fp16
        ln16_kernel<<<TT, 256, 0, stream>>>(xb, ln1_w, ln1_b, y16);

        // 2. Gate GEMMs (2 pairs via z): yi = (y@wi)*sig(y@wig+b); rr = sig(y@wf+b); og = sig(y@wog+b)
        //    128x64 tile: per-wave 64x32/mat -> 16 MFMA : 8 ds_read per K-step (m97 ratio)
        gemm16<128, 64, 32, 2, 0><<<dim3(MM/64, TT/128, 2), 256, 0, stream>>>(
            y16, EE, MM,
            wi_t, wig_t, wf_t, wog_t,
            wig_b, wf_b, wog_b,
            nullptr,
            yi16, rr16, og16, nullptr);

        // 3-5. scan h = r*h + yi ; g = softsign(h)*og (in place over yi16) ; mem_out
        scan_pass1<<<MM * CHUNKS / 256, 256, 0, stream>>>(yi16, rr16, Ac, Sc);
        scan_pass2<<<MM / 256, 256, 0, stream>>>(memb, Ac, Sc, H0, memoutb);
        scan_pass3<<<MM * CHUNKS / 256, 256, 0, stream>>>(yi16, rr16, og16, H0);

        // 6. x2 = x + g @ wo   (x2 == outb)
        gemm16<128, 64, 64, 1, 2><<<dim3(EE/64, TT/128), 256, 0, stream>>>(
            yi16, MM, EE,
            wo_t, nullptr, nullptr, nullptr,
            nullptr, nullptr, nullptr,
            xb,
            nullptr, nullptr, nullptr, x2);

        // 7. z = LN(x2) -> fp16 (into y16)
        ln16_kernel<<<TT, 256, 0, stream>>>(x2, ln2_w, ln2_b, y16);

        // 8. zi = (z@fwi)*sig(z@fwg+b)  (into og16)
        gemm16<128, 64, 32, 2, 1><<<dim3(MM/64, TT/128), 256, 0, stream>>>(
            y16, EE, MM,
            fwi_t, fwg_t, nullptr, nullptr,
            fwg_b, nullptr, nullptr,
            nullptr,
            og16, nullptr, nullptr, nullptr);

        // 9. out = x2 + zi @ fwo + fwo_b  (in place over the output slab; same-index RMW)
        gemm16<128, 64, 64, 1, 3><<<dim3(EE/64, TT/128), 256, 0, stream>>>(
            og16, MM, EE,
            fwo_t, nullptr, nullptr, nullptr,
            fwo_b, nullptr, nullptr,
            x2,
            nullptr, nullptr, nullptr, outb);
    }
}